// Round 1
// baseline (251.780 us; speedup 1.0000x reference)
//
#include <hip/hip_runtime.h>
#include <cstdint>
#include <cstddef>

#define NB 2
#define NL 2048
#define ND 1024
#define NH 16
#define NHD 64

typedef __bf16 bf16x8 __attribute__((ext_vector_type(8)));
typedef float f32x4 __attribute__((ext_vector_type(4)));

__device__ __forceinline__ void gload16(const void* g, void* l) {
  __builtin_amdgcn_global_load_lds(
      (__attribute__((address_space(1))) uint32_t*)(uintptr_t)g,
      (__attribute__((address_space(3))) uint32_t*)l, 16, 0, 0);
}

// ---------------- elementwise f32 -> bf16 ----------------
__global__ __launch_bounds__(256) void cvt_f32_bf16(const float* __restrict__ src,
                                                    __bf16* __restrict__ dst, int n4) {
  int i = blockIdx.x * 256 + threadIdx.x;
  if (i >= n4) return;
  float4 f = reinterpret_cast<const float4*>(src)[i];
  ushort4 u;
  u.x = __builtin_bit_cast(unsigned short, (__bf16)f.x);
  u.y = __builtin_bit_cast(unsigned short, (__bf16)f.y);
  u.z = __builtin_bit_cast(unsigned short, (__bf16)f.z);
  u.w = __builtin_bit_cast(unsigned short, (__bf16)f.w);
  reinterpret_cast<ushort4*>(dst)[i] = u;
}

// ---------------- 4x weight transpose+convert: Wt[n][k] = bf16(W[k][n]) ----------------
__global__ __launch_bounds__(256) void transpose_cvt4(
    const float* __restrict__ W0, const float* __restrict__ W1,
    const float* __restrict__ W2, const float* __restrict__ W3,
    __bf16* __restrict__ T0, __bf16* __restrict__ T1,
    __bf16* __restrict__ T2, __bf16* __restrict__ T3) {
  const float* W;
  __bf16* T;
  switch (blockIdx.z) {
    case 0: W = W0; T = T0; break;
    case 1: W = W1; T = T1; break;
    case 2: W = W2; T = T2; break;
    default: W = W3; T = T3; break;
  }
  __shared__ float tile[32][33];
  int tx = threadIdx.x, ty = threadIdx.y;
  int x0 = blockIdx.x * 32, y0 = blockIdx.y * 32;
#pragma unroll
  for (int r = 0; r < 4; r++)
    tile[ty + r * 8][tx] = W[(y0 + ty + r * 8) * ND + x0 + tx];
  __syncthreads();
#pragma unroll
  for (int r = 0; r < 4; r++)
    T[(x0 + ty + r * 8) * ND + y0 + tx] = (__bf16)tile[tx][ty + r * 8];
}

// ---------------- distance bins (head-independent) ----------------
__global__ __launch_bounds__(256) void bins_kernel(const float* __restrict__ pos,
                                                   unsigned char* __restrict__ bins) {
  int k = blockIdx.x * 256 + threadIdx.x;
  int q = blockIdx.y;
  int b = blockIdx.z;
  float qx = pos[(b * NL + q) * 3 + 0];
  float qy = pos[(b * NL + q) * 3 + 1];
  float qz = pos[(b * NL + q) * 3 + 2];
  float kx = pos[((size_t)b * NL + k) * 3 + 0];
  float ky = pos[((size_t)b * NL + k) * 3 + 1];
  float kz = pos[((size_t)b * NL + k) * 3 + 2];
  float dx = qx - kx, dy = qy - ky, dz = qz - kz;
  float d2 = dx * dx + dy * dy + dz * dz;
  float dist = sqrtf(d2);
  float t = (dist / 5.0f) * 32.0f;  // match reference op order
  int bin = (int)t;
  bin = bin > 32 ? 32 : bin;
  bins[((size_t)b * NL + q) * NL + k] = (unsigned char)bin;
}

// ---------------- shared bf16 GEMM: C = A[MxK] @ Bt[NxK]^T + bias ----------------
// mode 0: bf16 out, [b,h,l,hd] (head-split)     (Q, K projections)
// mode 1: bf16 out, [b,h,hd,l] (head-split, T)  (V projection)
// mode 2: f32 out, row-major MxN                (output projection)
__global__ __launch_bounds__(256) void gemm_bf16(
    const __bf16* __restrict__ A, const __bf16* __restrict__ Bt,
    const float* __restrict__ bias, void* __restrict__ Cout,
    int M, int N, int K, int mode) {
  __shared__ __bf16 As[64 * 64];
  __shared__ __bf16 Bs[128 * 64];
  const int tid = threadIdx.x;
  const int lane = tid & 63;
  const int wave = tid >> 6;
  const int nbm = M >> 6;
  const int bm = blockIdx.x % nbm;
  const int bn = blockIdx.x / nbm;
  const int wm = (wave >> 1) * 32;
  const int wn = (wave & 1) * 64;
  f32x4 acc[2][4] = {};
  const __bf16* Abase = A + (size_t)(bm * 64) * K;
  const __bf16* Bbase = Bt + (size_t)(bn * 128) * K;

  for (int kt = 0; kt < K; kt += 64) {
#pragma unroll
    for (int i = 0; i < 2; i++) {
      int lin = i * 256 + tid;
      int row = lin >> 3;
      int c = (lin & 7) ^ (row & 7);
      gload16(Abase + (size_t)row * K + kt + c * 8, (char*)As + lin * 16);
    }
#pragma unroll
    for (int i = 0; i < 4; i++) {
      int lin = i * 256 + tid;
      int row = lin >> 3;
      int c = (lin & 7) ^ (row & 7);
      gload16(Bbase + (size_t)row * K + kt + c * 8, (char*)Bs + lin * 16);
    }
    __syncthreads();
#pragma unroll
    for (int kk = 0; kk < 2; kk++) {
      const int cb = kk * 4 + (lane >> 4);
      bf16x8 af[2], bfr[4];
#pragma unroll
      for (int mf = 0; mf < 2; mf++) {
        int r = wm + mf * 16 + (lane & 15);
        af[mf] = *(const bf16x8*)((const char*)As + r * 128 + ((cb ^ (r & 7)) << 4));
      }
#pragma unroll
      for (int nf = 0; nf < 4; nf++) {
        int r = wn + nf * 16 + (lane & 15);
        bfr[nf] = *(const bf16x8*)((const char*)Bs + r * 128 + ((cb ^ (r & 7)) << 4));
      }
#pragma unroll
      for (int mf = 0; mf < 2; mf++)
#pragma unroll
        for (int nf = 0; nf < 4; nf++)
          acc[mf][nf] = __builtin_amdgcn_mfma_f32_16x16x32_bf16(af[mf], bfr[nf],
                                                                acc[mf][nf], 0, 0, 0);
    }
    __syncthreads();
  }

  const int rbase = (lane >> 4) << 2;
  const int cbase = lane & 15;
  if (mode == 2) {
    float* C = (float*)Cout;
#pragma unroll
    for (int mf = 0; mf < 2; mf++)
#pragma unroll
      for (int nf = 0; nf < 4; nf++) {
        int m0 = bm * 64 + wm + mf * 16 + rbase;
        int n = bn * 128 + wn + nf * 16 + cbase;
        float bv = bias[n];
#pragma unroll
        for (int j = 0; j < 4; j++)
          C[(size_t)(m0 + j) * N + n] = acc[mf][nf][j] + bv;
      }
  } else if (mode == 0) {
    __bf16* C = (__bf16*)Cout;
#pragma unroll
    for (int mf = 0; mf < 2; mf++)
#pragma unroll
      for (int nf = 0; nf < 4; nf++) {
        int m0 = bm * 64 + wm + mf * 16 + rbase;
        int n = bn * 128 + wn + nf * 16 + cbase;
        float bv = bias[n];
        int b = m0 >> 11, ls = m0 & (NL - 1);
        int h = n >> 6, d = n & 63;
        __bf16* base = C + ((size_t)((b * NH + h) * NL + ls)) * NHD + d;
#pragma unroll
        for (int j = 0; j < 4; j++)
          base[(size_t)j * NHD] = (__bf16)(acc[mf][nf][j] + bv);
      }
  } else {  // mode 1: V transposed [b,h,hd,l]
    __bf16* C = (__bf16*)Cout;
#pragma unroll
    for (int mf = 0; mf < 2; mf++)
#pragma unroll
      for (int nf = 0; nf < 4; nf++) {
        int m0 = bm * 64 + wm + mf * 16 + rbase;
        int n = bn * 128 + wn + nf * 16 + cbase;
        float bv = bias[n];
        int b = m0 >> 11, ls = m0 & (NL - 1);
        int h = n >> 6, d = n & 63;
        ushort4 u;
        u.x = __builtin_bit_cast(unsigned short, (__bf16)(acc[mf][nf][0] + bv));
        u.y = __builtin_bit_cast(unsigned short, (__bf16)(acc[mf][nf][1] + bv));
        u.z = __builtin_bit_cast(unsigned short, (__bf16)(acc[mf][nf][2] + bv));
        u.w = __builtin_bit_cast(unsigned short, (__bf16)(acc[mf][nf][3] + bv));
        *(ushort4*)(C + ((size_t)((b * NH + h) * NHD + d)) * NL + ls) = u;
      }
  }
}

// ---------------- flash attention with distance-bin bias ----------------
__global__ __launch_bounds__(256) void attn_kernel(
    const __bf16* __restrict__ Q, const __bf16* __restrict__ K,
    const __bf16* __restrict__ Vt, const unsigned char* __restrict__ bins,
    const float* __restrict__ emb, __bf16* __restrict__ outb) {
  __shared__ __bf16 Ks[64 * 64];
  __shared__ __bf16 Vs[64 * 64];
  __shared__ __bf16 Ps[4][16 * 64];
  __shared__ float embs[33];
  const int tid = threadIdx.x;
  const int lane = tid & 63;
  const int wave = tid >> 6;
  const int qt = blockIdx.x & 31;
  const int h = (blockIdx.x >> 5) & 15;
  const int b = blockIdx.x >> 9;
  if (tid < 33) embs[tid] = emb[tid * NH + h];
  const int q0 = qt * 64 + wave * 16;
  const int rbase = (lane >> 4) << 2;

  const __bf16* Qbase =
      Q + ((size_t)((b * NH + h) * NL + q0 + (lane & 15))) * NHD + ((lane >> 4) * 8);
  bf16x8 qf0 = *(const bf16x8*)(Qbase);
  bf16x8 qf1 = *(const bf16x8*)(Qbase + 32);

  const unsigned char* binrow[4];
#pragma unroll
  for (int j = 0; j < 4; j++)
    binrow[j] = bins + ((size_t)b * NL + (q0 + rbase + j)) * NL;

  float mrun[4] = {-1e30f, -1e30f, -1e30f, -1e30f};
  float lsum[4] = {0.f, 0.f, 0.f, 0.f};
  f32x4 oacc[4] = {};
  const __bf16* Kbase = K + ((size_t)(b * NH + h) * NL) * NHD;
  const __bf16* Vbase = Vt + ((size_t)(b * NH + h) * NHD) * NL;
  char* psw = (char*)&Ps[wave][0];

  for (int kt = 0; kt < NL; kt += 64) {
#pragma unroll
    for (int i = 0; i < 2; i++) {
      int lin = i * 256 + tid;
      int row = lin >> 3;
      int c = (lin & 7) ^ (row & 7);
      gload16(Kbase + (size_t)(kt + row) * NHD + c * 8, (char*)Ks + lin * 16);
      gload16(Vbase + (size_t)row * NL + kt + c * 8, (char*)Vs + lin * 16);
    }
    __syncthreads();

    f32x4 sacc[4] = {};
#pragma unroll
    for (int kk = 0; kk < 2; kk++) {
      const int cb = kk * 4 + (lane >> 4);
      bf16x8 aq = (kk == 0) ? qf0 : qf1;
#pragma unroll
      for (int kf = 0; kf < 4; kf++) {
        int r = kf * 16 + (lane & 15);
        bf16x8 kb = *(const bf16x8*)((const char*)Ks + r * 128 + ((cb ^ (r & 7)) << 4));
        sacc[kf] = __builtin_amdgcn_mfma_f32_16x16x32_bf16(aq, kb, sacc[kf], 0, 0, 0);
      }
    }

    // softmax (online): s = dot/8 + dist_emb[bin][h]
    float p[4][4];
#pragma unroll
    for (int kf = 0; kf < 4; kf++) {
      int kc = kt + kf * 16 + (lane & 15);
#pragma unroll
      for (int j = 0; j < 4; j++) {
        int bin = binrow[j][kc];
        p[kf][j] = sacc[kf][j] * 0.125f + embs[bin];
      }
    }
#pragma unroll
    for (int j = 0; j < 4; j++) {
      float mt = fmaxf(fmaxf(p[0][j], p[1][j]), fmaxf(p[2][j], p[3][j]));
      mt = fmaxf(mt, __shfl_xor(mt, 1, 64));
      mt = fmaxf(mt, __shfl_xor(mt, 2, 64));
      mt = fmaxf(mt, __shfl_xor(mt, 4, 64));
      mt = fmaxf(mt, __shfl_xor(mt, 8, 64));
      float mn = fmaxf(mrun[j], mt);
      float corr = __expf(mrun[j] - mn);
      mrun[j] = mn;
      float rs = 0.f;
#pragma unroll
      for (int kf = 0; kf < 4; kf++) {
        p[kf][j] = __expf(p[kf][j] - mn);
        rs += p[kf][j];
      }
      rs += __shfl_xor(rs, 1, 64);
      rs += __shfl_xor(rs, 2, 64);
      rs += __shfl_xor(rs, 4, 64);
      rs += __shfl_xor(rs, 8, 64);
      lsum[j] = lsum[j] * corr + rs;
#pragma unroll
      for (int df = 0; df < 4; df++) oacc[df][j] *= corr;
    }

    // P -> LDS (swizzled), then PV
#pragma unroll
    for (int kf = 0; kf < 4; kf++)
#pragma unroll
      for (int j = 0; j < 4; j++) {
        int prow = rbase + j;
        int pcol = kf * 16 + (lane & 15);
        int off = prow * 128 + ((((pcol >> 3) ^ (prow & 7)) << 4) | ((pcol & 7) << 1));
        *(__bf16*)(psw + off) = (__bf16)p[kf][j];
      }
    __syncthreads();
#pragma unroll
    for (int kk = 0; kk < 2; kk++) {
      const int cb = kk * 4 + (lane >> 4);
      int pr = lane & 15;
      bf16x8 pa = *(const bf16x8*)(psw + pr * 128 + ((cb ^ (pr & 7)) << 4));
#pragma unroll
      for (int df = 0; df < 4; df++) {
        int r = df * 16 + (lane & 15);
        bf16x8 vb = *(const bf16x8*)((const char*)Vs + r * 128 + ((cb ^ (r & 7)) << 4));
        oacc[df] = __builtin_amdgcn_mfma_f32_16x16x32_bf16(pa, vb, oacc[df], 0, 0, 0);
      }
    }
    __syncthreads();
  }

#pragma unroll
  for (int j = 0; j < 4; j++) {
    float inv = 1.0f / lsum[j];
    int qr = q0 + rbase + j;
    __bf16* obase = outb + ((size_t)(b * NL + qr)) * ND + h * NHD + (lane & 15);
#pragma unroll
    for (int df = 0; df < 4; df++)
      obase[df * 16] = (__bf16)(oacc[df][j] * inv);
  }
}

extern "C" void kernel_launch(void* const* d_in, const int* in_sizes, int n_in,
                              void* d_out, int out_size, void* d_ws, size_t ws_size,
                              hipStream_t stream) {
  const float* query = (const float*)d_in[0];
  const float* key = (const float*)d_in[1];
  const float* value = (const float*)d_in[2];
  const float* pos = (const float*)d_in[3];
  const float* Wq = (const float*)d_in[4];
  const float* bq = (const float*)d_in[5];
  const float* Wk = (const float*)d_in[6];
  const float* bk = (const float*)d_in[7];
  const float* Wv = (const float*)d_in[8];
  const float* bv = (const float*)d_in[9];
  const float* Wo = (const float*)d_in[10];
  const float* bo = (const float*)d_in[11];
  const float* emb = (const float*)d_in[12];

  if (ws_size < (64ull << 20)) return;  // need 64MB scratch
  char* ws = (char*)d_ws;
  const size_t MB = 1ull << 20;
  __bf16* qb = (__bf16*)(ws + 0 * MB);  // reused as attnb after GEMM1-Q
  __bf16* kb = (__bf16*)(ws + 8 * MB);
  __bf16* vb = (__bf16*)(ws + 16 * MB);
  __bf16* Wq_t = (__bf16*)(ws + 24 * MB);
  __bf16* Wk_t = (__bf16*)(ws + 26 * MB);
  __bf16* Wv_t = (__bf16*)(ws + 28 * MB);
  __bf16* Wo_t = (__bf16*)(ws + 30 * MB);
  __bf16* Qp = (__bf16*)(ws + 32 * MB);
  __bf16* Kp = (__bf16*)(ws + 40 * MB);
  __bf16* Vtp = (__bf16*)(ws + 48 * MB);
  unsigned char* binsb = (unsigned char*)(ws + 56 * MB);
  __bf16* attnb = qb;

  const int n4 = NB * NL * ND / 4;
  cvt_f32_bf16<<<n4 / 256, 256, 0, stream>>>(query, qb, n4);
  cvt_f32_bf16<<<n4 / 256, 256, 0, stream>>>(key, kb, n4);
  cvt_f32_bf16<<<n4 / 256, 256, 0, stream>>>(value, vb, n4);
  transpose_cvt4<<<dim3(32, 32, 4), dim3(32, 8), 0, stream>>>(Wq, Wk, Wv, Wo, Wq_t,
                                                              Wk_t, Wv_t, Wo_t);
  bins_kernel<<<dim3(NL / 256, NL, NB), 256, 0, stream>>>(pos, binsb);

  const int M = NB * NL, N = ND, Kd = ND;
  gemm_bf16<<<(M / 64) * (N / 128), 256, 0, stream>>>(qb, Wq_t, bq, Qp, M, N, Kd, 0);
  gemm_bf16<<<(M / 64) * (N / 128), 256, 0, stream>>>(kb, Wk_t, bk, Kp, M, N, Kd, 0);
  gemm_bf16<<<(M / 64) * (N / 128), 256, 0, stream>>>(vb, Wv_t, bv, Vtp, M, N, Kd, 1);

  attn_kernel<<<NB * NH * (NL / 64), 256, 0, stream>>>(Qp, Kp, Vtp, binsb, emb, attnb);

  gemm_bf16<<<(M / 64) * (N / 128), 256, 0, stream>>>(attnb, Wo_t, bo, (float*)d_out,
                                                      M, N, Kd, 2);
}

// Round 2
// 227.616 us; speedup vs baseline: 1.1062x; 1.1062x over previous
//
#include <hip/hip_runtime.h>
#include <cstdint>
#include <cstddef>

#define NB 2
#define NL 2048
#define ND 1024
#define NH 16
#define NHD 64

typedef __bf16 bf16x8 __attribute__((ext_vector_type(8)));
typedef float f32x4 __attribute__((ext_vector_type(4)));

__device__ __forceinline__ void gload16(const void* g, void* l) {
  __builtin_amdgcn_global_load_lds(
      (__attribute__((address_space(1))) uint32_t*)(uintptr_t)g,
      (__attribute__((address_space(3))) uint32_t*)l, 16, 0, 0);
}

// ---------------- fused 3x elementwise f32 -> bf16 ----------------
__global__ __launch_bounds__(256) void cvt3_f32_bf16(
    const float* __restrict__ s0, const float* __restrict__ s1,
    const float* __restrict__ s2, __bf16* __restrict__ d0,
    __bf16* __restrict__ d1, __bf16* __restrict__ d2, int n4) {
  const float* src;
  __bf16* dst;
  switch (blockIdx.y) {
    case 0: src = s0; dst = d0; break;
    case 1: src = s1; dst = d1; break;
    default: src = s2; dst = d2; break;
  }
  int i = blockIdx.x * 256 + threadIdx.x;
  if (i >= n4) return;
  float4 f = reinterpret_cast<const float4*>(src)[i];
  ushort4 u;
  u.x = __builtin_bit_cast(unsigned short, (__bf16)f.x);
  u.y = __builtin_bit_cast(unsigned short, (__bf16)f.y);
  u.z = __builtin_bit_cast(unsigned short, (__bf16)f.z);
  u.w = __builtin_bit_cast(unsigned short, (__bf16)f.w);
  reinterpret_cast<ushort4*>(dst)[i] = u;
}

// ---------------- 4x weight transpose+convert: Wt[n][k] = bf16(W[k][n]) ----------------
__global__ __launch_bounds__(256) void transpose_cvt4(
    const float* __restrict__ W0, const float* __restrict__ W1,
    const float* __restrict__ W2, const float* __restrict__ W3,
    __bf16* __restrict__ T0, __bf16* __restrict__ T1,
    __bf16* __restrict__ T2, __bf16* __restrict__ T3) {
  const float* W;
  __bf16* T;
  switch (blockIdx.z) {
    case 0: W = W0; T = T0; break;
    case 1: W = W1; T = T1; break;
    case 2: W = W2; T = T2; break;
    default: W = W3; T = T3; break;
  }
  __shared__ float tile[32][33];
  int tx = threadIdx.x, ty = threadIdx.y;
  int x0 = blockIdx.x * 32, y0 = blockIdx.y * 32;
#pragma unroll
  for (int r = 0; r < 4; r++)
    tile[ty + r * 8][tx] = W[(y0 + ty + r * 8) * ND + x0 + tx];
  __syncthreads();
#pragma unroll
  for (int r = 0; r < 4; r++)
    T[(x0 + ty + r * 8) * ND + y0 + tx] = (__bf16)tile[tx][ty + r * 8];
}

// ---------------- distance bins, 4 k per thread ----------------
__global__ __launch_bounds__(256) void bins_kernel(const float* __restrict__ pos,
                                                   unsigned char* __restrict__ bins) {
  int k0 = (blockIdx.x * 256 + threadIdx.x) * 4;
  int q = blockIdx.y;
  int b = blockIdx.z;
  float qx = pos[((size_t)b * NL + q) * 3 + 0];
  float qy = pos[((size_t)b * NL + q) * 3 + 1];
  float qz = pos[((size_t)b * NL + q) * 3 + 2];
  const float* kp = pos + ((size_t)b * NL + k0) * 3;
  float4 p0 = *(const float4*)(kp + 0);
  float4 p1 = *(const float4*)(kp + 4);
  float4 p2 = *(const float4*)(kp + 8);
  float kx[4] = {p0.x, p0.w, p1.z, p2.y};
  float ky[4] = {p0.y, p1.x, p1.w, p2.z};
  float kz[4] = {p0.z, p1.y, p2.x, p2.w};
  uchar4 out;
  unsigned char* o = (unsigned char*)&out;
#pragma unroll
  for (int j = 0; j < 4; j++) {
    float dx = qx - kx[j], dy = qy - ky[j], dz = qz - kz[j];
    float dist = sqrtf(dx * dx + dy * dy + dz * dz);
    float t = (dist / 5.0f) * 32.0f;  // match reference op order
    int bin = (int)t;
    bin = bin > 32 ? 32 : bin;
    o[j] = (unsigned char)bin;
  }
  *(uchar4*)(bins + ((size_t)b * NL + q) * NL + k0) = out;
}

// ---------------- merged QKV projection GEMM, 128x128 tile ----------------
// z = blockIdx.x>>8 selects {Q,K,V}; z<2 -> [b,h,l,hd], z==2 -> [b,h,hd,l]
__global__ __launch_bounds__(256) void gemm_qkv(
    const __bf16* __restrict__ Aq, const __bf16* __restrict__ Ak,
    const __bf16* __restrict__ Av, const __bf16* __restrict__ Wqt,
    const __bf16* __restrict__ Wkt, const __bf16* __restrict__ Wvt,
    const float* __restrict__ bq, const float* __restrict__ bk,
    const float* __restrict__ bv, __bf16* __restrict__ Qp,
    __bf16* __restrict__ Kp, __bf16* __restrict__ Vtp) {
  __shared__ __bf16 As[128 * 64];
  __shared__ __bf16 Bs[128 * 64];
  const int tid = threadIdx.x;
  const int lane = tid & 63;
  const int wave = tid >> 6;
  const int z = blockIdx.x >> 8;
  const int r = blockIdx.x & 255;
  const int bm = r & 31;
  const int bn = r >> 5;
  const __bf16* A = (z == 0) ? Aq : (z == 1) ? Ak : Av;
  const __bf16* Bt = (z == 0) ? Wqt : (z == 1) ? Wkt : Wvt;
  const float* bias = (z == 0) ? bq : (z == 1) ? bk : bv;
  __bf16* C = (z == 0) ? Qp : (z == 1) ? Kp : Vtp;

  const int wm = (wave >> 1) * 64;
  const int wn = (wave & 1) * 64;
  f32x4 acc[4][4] = {};
  const __bf16* Abase = A + (size_t)(bm * 128) * ND;
  const __bf16* Bbase = Bt + (size_t)(bn * 128) * ND;

  for (int kt = 0; kt < ND; kt += 64) {
#pragma unroll
    for (int i = 0; i < 4; i++) {
      int lin = i * 256 + tid;
      int row = lin >> 3;
      int c = (lin & 7) ^ (row & 7);
      gload16(Abase + (size_t)row * ND + kt + c * 8, (char*)As + lin * 16);
    }
#pragma unroll
    for (int i = 0; i < 4; i++) {
      int lin = i * 256 + tid;
      int row = lin >> 3;
      int c = (lin & 7) ^ (row & 7);
      gload16(Bbase + (size_t)row * ND + kt + c * 8, (char*)Bs + lin * 16);
    }
    __syncthreads();
#pragma unroll
    for (int kk = 0; kk < 2; kk++) {
      const int cb = kk * 4 + (lane >> 4);
      bf16x8 af[4], bfr[4];
#pragma unroll
      for (int mf = 0; mf < 4; mf++) {
        int rr = wm + mf * 16 + (lane & 15);
        af[mf] = *(const bf16x8*)((const char*)As + rr * 128 + ((cb ^ (rr & 7)) << 4));
      }
#pragma unroll
      for (int nf = 0; nf < 4; nf++) {
        int rr = wn + nf * 16 + (lane & 15);
        bfr[nf] = *(const bf16x8*)((const char*)Bs + rr * 128 + ((cb ^ (rr & 7)) << 4));
      }
      __builtin_amdgcn_s_setprio(1);
#pragma unroll
      for (int mf = 0; mf < 4; mf++)
#pragma unroll
        for (int nf = 0; nf < 4; nf++)
          acc[mf][nf] = __builtin_amdgcn_mfma_f32_16x16x32_bf16(af[mf], bfr[nf],
                                                                acc[mf][nf], 0, 0, 0);
      __builtin_amdgcn_s_setprio(0);
    }
    __syncthreads();
  }

  const int rbase = (lane >> 4) << 2;
  const int cbase = lane & 15;
  if (z < 2) {
#pragma unroll
    for (int mf = 0; mf < 4; mf++)
#pragma unroll
      for (int nf = 0; nf < 4; nf++) {
        int m0 = bm * 128 + wm + mf * 16 + rbase;
        int n = bn * 128 + wn + nf * 16 + cbase;
        float bvv = bias[n];
        int b = m0 >> 11, ls = m0 & (NL - 1);
        int h = n >> 6, d = n & 63;
        __bf16* base = C + ((size_t)((b * NH + h) * NL + ls)) * NHD + d;
#pragma unroll
        for (int j = 0; j < 4; j++)
          base[(size_t)j * NHD] = (__bf16)(acc[mf][nf][j] + bvv);
      }
  } else {
#pragma unroll
    for (int mf = 0; mf < 4; mf++)
#pragma unroll
      for (int nf = 0; nf < 4; nf++) {
        int m0 = bm * 128 + wm + mf * 16 + rbase;
        int n = bn * 128 + wn + nf * 16 + cbase;
        float bvv = bias[n];
        int b = m0 >> 11, ls = m0 & (NL - 1);
        int h = n >> 6, d = n & 63;
        ushort4 u;
        u.x = __builtin_bit_cast(unsigned short, (__bf16)(acc[mf][nf][0] + bvv));
        u.y = __builtin_bit_cast(unsigned short, (__bf16)(acc[mf][nf][1] + bvv));
        u.z = __builtin_bit_cast(unsigned short, (__bf16)(acc[mf][nf][2] + bvv));
        u.w = __builtin_bit_cast(unsigned short, (__bf16)(acc[mf][nf][3] + bvv));
        *(ushort4*)(C + ((size_t)((b * NH + h) * NHD + d)) * NL + ls) = u;
      }
  }
}

// ---------------- output projection GEMM (64x128 tile, f32 out) ----------------
__global__ __launch_bounds__(256) void gemm_out(
    const __bf16* __restrict__ A, const __bf16* __restrict__ Bt,
    const float* __restrict__ bias, float* __restrict__ C) {
  __shared__ __bf16 As[64 * 64];
  __shared__ __bf16 Bs[128 * 64];
  const int tid = threadIdx.x;
  const int lane = tid & 63;
  const int wave = tid >> 6;
  const int nbm = (NB * NL) >> 6;
  const int bm = blockIdx.x % nbm;
  const int bn = blockIdx.x / nbm;
  const int wm = (wave >> 1) * 32;
  const int wn = (wave & 1) * 64;
  f32x4 acc[2][4] = {};
  const __bf16* Abase = A + (size_t)(bm * 64) * ND;
  const __bf16* Bbase = Bt + (size_t)(bn * 128) * ND;

  for (int kt = 0; kt < ND; kt += 64) {
#pragma unroll
    for (int i = 0; i < 2; i++) {
      int lin = i * 256 + tid;
      int row = lin >> 3;
      int c = (lin & 7) ^ (row & 7);
      gload16(Abase + (size_t)row * ND + kt + c * 8, (char*)As + lin * 16);
    }
#pragma unroll
    for (int i = 0; i < 4; i++) {
      int lin = i * 256 + tid;
      int row = lin >> 3;
      int c = (lin & 7) ^ (row & 7);
      gload16(Bbase + (size_t)row * ND + kt + c * 8, (char*)Bs + lin * 16);
    }
    __syncthreads();
#pragma unroll
    for (int kk = 0; kk < 2; kk++) {
      const int cb = kk * 4 + (lane >> 4);
      bf16x8 af[2], bfr[4];
#pragma unroll
      for (int mf = 0; mf < 2; mf++) {
        int rr = wm + mf * 16 + (lane & 15);
        af[mf] = *(const bf16x8*)((const char*)As + rr * 128 + ((cb ^ (rr & 7)) << 4));
      }
#pragma unroll
      for (int nf = 0; nf < 4; nf++) {
        int rr = wn + nf * 16 + (lane & 15);
        bfr[nf] = *(const bf16x8*)((const char*)Bs + rr * 128 + ((cb ^ (rr & 7)) << 4));
      }
      __builtin_amdgcn_s_setprio(1);
#pragma unroll
      for (int mf = 0; mf < 2; mf++)
#pragma unroll
        for (int nf = 0; nf < 4; nf++)
          acc[mf][nf] = __builtin_amdgcn_mfma_f32_16x16x32_bf16(af[mf], bfr[nf],
                                                                acc[mf][nf], 0, 0, 0);
      __builtin_amdgcn_s_setprio(0);
    }
    __syncthreads();
  }

  const int rbase = (lane >> 4) << 2;
  const int cbase = lane & 15;
#pragma unroll
  for (int mf = 0; mf < 2; mf++)
#pragma unroll
    for (int nf = 0; nf < 4; nf++) {
      int m0 = bm * 64 + wm + mf * 16 + rbase;
      int n = bn * 128 + wn + nf * 16 + cbase;
      float bvv = bias[n];
#pragma unroll
      for (int j = 0; j < 4; j++)
        C[(size_t)(m0 + j) * ND + n] = acc[mf][nf][j] + bvv;
    }
}

// ---------------- flash attention, double-buffered K/V, counted vmcnt ----------------
__global__ __launch_bounds__(256) void attn_kernel(
    const __bf16* __restrict__ Q, const __bf16* __restrict__ K,
    const __bf16* __restrict__ Vt, const unsigned char* __restrict__ bins,
    const float* __restrict__ emb, __bf16* __restrict__ outb) {
  __shared__ __bf16 Ks[2][64 * 64];
  __shared__ __bf16 Vs[2][64 * 64];
  __shared__ __bf16 Ps[4][16 * 64];
  __shared__ float embs[33];
  const int tid = threadIdx.x;
  const int lane = tid & 63;
  const int wave = tid >> 6;
  const int qt = blockIdx.x & 31;
  const int h = (blockIdx.x >> 5) & 15;
  const int b = blockIdx.x >> 9;
  if (tid < 33) embs[tid] = emb[tid * NH + h];
  const int q0 = qt * 64 + wave * 16;
  const int rbase = (lane >> 4) << 2;

  const __bf16* Qbase =
      Q + ((size_t)((b * NH + h) * NL + q0 + (lane & 15))) * NHD + ((lane >> 4) * 8);
  bf16x8 qf0 = *(const bf16x8*)(Qbase);
  bf16x8 qf1 = *(const bf16x8*)(Qbase + 32);

  const unsigned char* binrow[4];
#pragma unroll
  for (int j = 0; j < 4; j++)
    binrow[j] = bins + ((size_t)b * NL + (q0 + rbase + j)) * NL;

  float mrun[4] = {-1e30f, -1e30f, -1e30f, -1e30f};
  float lsum[4] = {0.f, 0.f, 0.f, 0.f};
  f32x4 oacc[4] = {};
  const __bf16* Kbase = K + ((size_t)(b * NH + h) * NL) * NHD;
  const __bf16* Vbase = Vt + ((size_t)(b * NH + h) * NHD) * NL;
  char* psw = (char*)&Ps[wave][0];

  // staging: 4 gload16 per thread (2 K + 2 V)
#define STAGE(bufi, ktt)                                                         \
  {                                                                              \
    _Pragma("unroll") for (int i = 0; i < 2; i++) {                              \
      int lin = i * 256 + tid;                                                   \
      int row = lin >> 3;                                                        \
      int c = (lin & 7) ^ (row & 7);                                             \
      gload16(Kbase + (size_t)((ktt) + row) * NHD + c * 8,                       \
              (char*)&Ks[bufi][0] + lin * 16);                                   \
      gload16(Vbase + (size_t)row * NL + (ktt) + c * 8,                          \
              (char*)&Vs[bufi][0] + lin * 16);                                   \
    }                                                                            \
  }

  unsigned char bcur[4][4], bnxt[4][4];
#define LOADBINS(dst, ktt)                                                       \
  {                                                                              \
    _Pragma("unroll") for (int kf = 0; kf < 4; kf++) {                           \
      int kc = (ktt) + kf * 16 + (lane & 15);                                    \
      _Pragma("unroll") for (int j = 0; j < 4; j++) dst[kf][j] = binrow[j][kc];  \
    }                                                                            \
  }

  STAGE(0, 0);
  LOADBINS(bcur, 0);
  __syncthreads();  // drains prologue staging + embs visible

  const int NT = NL / 64;
  for (int t = 0; t < NT; t++) {
    const int kt = t * 64;
    __builtin_amdgcn_s_barrier();  // A: all waves done reading buf[(t-1)&1]
    if (t + 1 < NT) {
      STAGE((t + 1) & 1, kt + 64);
      asm volatile("s_waitcnt vmcnt(4)" ::: "memory");
    } else {
      asm volatile("s_waitcnt vmcnt(0)" ::: "memory");
    }
    __builtin_amdgcn_s_barrier();  // B: tile t data visible to all waves
    if (t + 1 < NT) LOADBINS(bnxt, kt + 64);

    const int cur = t & 1;
    f32x4 sacc[4] = {};
#pragma unroll
    for (int kk = 0; kk < 2; kk++) {
      const int cb = kk * 4 + (lane >> 4);
      bf16x8 aq = (kk == 0) ? qf0 : qf1;
      __builtin_amdgcn_s_setprio(1);
#pragma unroll
      for (int kf = 0; kf < 4; kf++) {
        int rr = kf * 16 + (lane & 15);
        bf16x8 kb =
            *(const bf16x8*)((const char*)&Ks[cur][0] + rr * 128 + ((cb ^ (rr & 7)) << 4));
        sacc[kf] = __builtin_amdgcn_mfma_f32_16x16x32_bf16(aq, kb, sacc[kf], 0, 0, 0);
      }
      __builtin_amdgcn_s_setprio(0);
    }

    // online softmax: s = dot/8 + dist_emb[bin][h]
    float p[4][4];
#pragma unroll
    for (int kf = 0; kf < 4; kf++)
#pragma unroll
      for (int j = 0; j < 4; j++)
        p[kf][j] = sacc[kf][j] * 0.125f + embs[bcur[kf][j]];
#pragma unroll
    for (int j = 0; j < 4; j++) {
      float mt = fmaxf(fmaxf(p[0][j], p[1][j]), fmaxf(p[2][j], p[3][j]));
      mt = fmaxf(mt, __shfl_xor(mt, 1, 64));
      mt = fmaxf(mt, __shfl_xor(mt, 2, 64));
      mt = fmaxf(mt, __shfl_xor(mt, 4, 64));
      mt = fmaxf(mt, __shfl_xor(mt, 8, 64));
      float mn = fmaxf(mrun[j], mt);
      float corr = __expf(mrun[j] - mn);
      mrun[j] = mn;
      float rs = 0.f;
#pragma unroll
      for (int kf = 0; kf < 4; kf++) {
        p[kf][j] = __expf(p[kf][j] - mn);
        rs += p[kf][j];
      }
      rs += __shfl_xor(rs, 1, 64);
      rs += __shfl_xor(rs, 2, 64);
      rs += __shfl_xor(rs, 4, 64);
      rs += __shfl_xor(rs, 8, 64);
      lsum[j] = lsum[j] * corr + rs;
#pragma unroll
      for (int df = 0; df < 4; df++) oacc[df][j] *= corr;
    }

    // P -> per-wave LDS (swizzled), then PV
#pragma unroll
    for (int kf = 0; kf < 4; kf++)
#pragma unroll
      for (int j = 0; j < 4; j++) {
        int prow = rbase + j;
        int pcol = kf * 16 + (lane & 15);
        int off = prow * 128 + ((((pcol >> 3) ^ (prow & 7)) << 4) | ((pcol & 7) << 1));
        *(__bf16*)(psw + off) = (__bf16)p[kf][j];
      }
#pragma unroll
    for (int kk = 0; kk < 2; kk++) {
      const int cb = kk * 4 + (lane >> 4);
      int pr = lane & 15;
      bf16x8 pa = *(const bf16x8*)(psw + pr * 128 + ((cb ^ (pr & 7)) << 4));
      __builtin_amdgcn_s_setprio(1);
#pragma unroll
      for (int df = 0; df < 4; df++) {
        int rr = df * 16 + (lane & 15);
        bf16x8 vb =
            *(const bf16x8*)((const char*)&Vs[cur][0] + rr * 128 + ((cb ^ (rr & 7)) << 4));
        oacc[df] = __builtin_amdgcn_mfma_f32_16x16x32_bf16(pa, vb, oacc[df], 0, 0, 0);
      }
      __builtin_amdgcn_s_setprio(0);
    }

#pragma unroll
    for (int kf = 0; kf < 4; kf++)
#pragma unroll
      for (int j = 0; j < 4; j++) bcur[kf][j] = bnxt[kf][j];
  }

#pragma unroll
  for (int j = 0; j < 4; j++) {
    float inv = 1.0f / lsum[j];
    int qr = q0 + rbase + j;
    __bf16* obase = outb + ((size_t)(b * NL + qr)) * ND + h * NHD + (lane & 15);
#pragma unroll
    for (int df = 0; df < 4; df++)
      obase[df * 16] = (__bf16)(oacc[df][j] * inv);
  }
#undef STAGE
#undef LOADBINS
}

extern "C" void kernel_launch(void* const* d_in, const int* in_sizes, int n_in,
                              void* d_out, int out_size, void* d_ws, size_t ws_size,
                              hipStream_t stream) {
  const float* query = (const float*)d_in[0];
  const float* key = (const float*)d_in[1];
  const float* value = (const float*)d_in[2];
  const float* pos = (const float*)d_in[3];
  const float* Wq = (const float*)d_in[4];
  const float* bq = (const float*)d_in[5];
  const float* Wk = (const float*)d_in[6];
  const float* bk = (const float*)d_in[7];
  const float* Wv = (const float*)d_in[8];
  const float* bv = (const float*)d_in[9];
  const float* Wo = (const float*)d_in[10];
  const float* bo = (const float*)d_in[11];
  const float* emb = (const float*)d_in[12];

  if (ws_size < (64ull << 20)) return;  // need 64MB scratch
  char* ws = (char*)d_ws;
  const size_t MB = 1ull << 20;
  __bf16* qb = (__bf16*)(ws + 0 * MB);  // reused as attn output buffer
  __bf16* kb = (__bf16*)(ws + 8 * MB);
  __bf16* vb = (__bf16*)(ws + 16 * MB);
  __bf16* Wq_t = (__bf16*)(ws + 24 * MB);
  __bf16* Wk_t = (__bf16*)(ws + 26 * MB);
  __bf16* Wv_t = (__bf16*)(ws + 28 * MB);
  __bf16* Wo_t = (__bf16*)(ws + 30 * MB);
  __bf16* Qp = (__bf16*)(ws + 32 * MB);
  __bf16* Kp = (__bf16*)(ws + 40 * MB);
  __bf16* Vtp = (__bf16*)(ws + 48 * MB);
  unsigned char* binsb = (unsigned char*)(ws + 56 * MB);
  __bf16* attnb = qb;

  const int n4 = NB * NL * ND / 4;
  cvt3_f32_bf16<<<dim3(n4 / 256, 3), 256, 0, stream>>>(query, key, value, qb, kb, vb,
                                                       n4);
  transpose_cvt4<<<dim3(32, 32, 4), dim3(32, 8), 0, stream>>>(Wq, Wk, Wv, Wo, Wq_t,
                                                              Wk_t, Wv_t, Wo_t);
  bins_kernel<<<dim3(NL / 1024, NL, NB), 256, 0, stream>>>(pos, binsb);

  gemm_qkv<<<3 * 256, 256, 0, stream>>>(qb, kb, vb, Wq_t, Wk_t, Wv_t, bq, bk, bv, Qp,
                                        Kp, Vtp);

  attn_kernel<<<NB * NH * (NL / 64), 256, 0, stream>>>(Qp, Kp, Vtp, binsb, emb, attnb);

  gemm_out<<<((NB * NL) / 64) * (ND / 128), 256, 0, stream>>>(attnb, Wo_t, bo,
                                                              (float*)d_out);
}

// Round 3
// 171.682 us; speedup vs baseline: 1.4666x; 1.3258x over previous
//
#include <hip/hip_runtime.h>
#include <cstdint>
#include <cstddef>

#define NB 2
#define NL 2048
#define ND 1024
#define NH 16
#define NHD 64

typedef __bf16 bf16x8 __attribute__((ext_vector_type(8)));
typedef float f32x4 __attribute__((ext_vector_type(4)));

__device__ __forceinline__ void gload16(const void* g, void* l) {
  __builtin_amdgcn_global_load_lds(
      (__attribute__((address_space(1))) uint32_t*)(uintptr_t)g,
      (__attribute__((address_space(3))) uint32_t*)l, 16, 0, 0);
}

// ---------------- fused 3x elementwise f32 -> bf16 ----------------
__global__ __launch_bounds__(256) void cvt3_f32_bf16(
    const float* __restrict__ s0, const float* __restrict__ s1,
    const float* __restrict__ s2, __bf16* __restrict__ d0,
    __bf16* __restrict__ d1, __bf16* __restrict__ d2, int n4) {
  const float* src;
  __bf16* dst;
  switch (blockIdx.y) {
    case 0: src = s0; dst = d0; break;
    case 1: src = s1; dst = d1; break;
    default: src = s2; dst = d2; break;
  }
  int i = blockIdx.x * 256 + threadIdx.x;
  if (i >= n4) return;
  float4 f = reinterpret_cast<const float4*>(src)[i];
  ushort4 u;
  u.x = __builtin_bit_cast(unsigned short, (__bf16)f.x);
  u.y = __builtin_bit_cast(unsigned short, (__bf16)f.y);
  u.z = __builtin_bit_cast(unsigned short, (__bf16)f.z);
  u.w = __builtin_bit_cast(unsigned short, (__bf16)f.w);
  reinterpret_cast<ushort4*>(dst)[i] = u;
}

// ---------------- 4x weight transpose+convert: Wt[n][k] = bf16(W[k][n]) ----------------
__global__ __launch_bounds__(256) void transpose_cvt4(
    const float* __restrict__ W0, const float* __restrict__ W1,
    const float* __restrict__ W2, const float* __restrict__ W3,
    __bf16* __restrict__ T0, __bf16* __restrict__ T1,
    __bf16* __restrict__ T2, __bf16* __restrict__ T3) {
  const float* W;
  __bf16* T;
  switch (blockIdx.z) {
    case 0: W = W0; T = T0; break;
    case 1: W = W1; T = T1; break;
    case 2: W = W2; T = T2; break;
    default: W = W3; T = T3; break;
  }
  __shared__ float tile[32][33];
  int tx = threadIdx.x, ty = threadIdx.y;
  int x0 = blockIdx.x * 32, y0 = blockIdx.y * 32;
#pragma unroll
  for (int r = 0; r < 4; r++)
    tile[ty + r * 8][tx] = W[(y0 + ty + r * 8) * ND + x0 + tx];
  __syncthreads();
#pragma unroll
  for (int r = 0; r < 4; r++)
    T[(x0 + ty + r * 8) * ND + y0 + tx] = (__bf16)tile[tx][ty + r * 8];
}

// ---------------- distance bins, 4 k per thread ----------------
__global__ __launch_bounds__(256) void bins_kernel(const float* __restrict__ pos,
                                                   unsigned char* __restrict__ bins) {
  int k0 = (blockIdx.x * 256 + threadIdx.x) * 4;
  int q = blockIdx.y;
  int b = blockIdx.z;
  float qx = pos[((size_t)b * NL + q) * 3 + 0];
  float qy = pos[((size_t)b * NL + q) * 3 + 1];
  float qz = pos[((size_t)b * NL + q) * 3 + 2];
  const float* kp = pos + ((size_t)b * NL + k0) * 3;
  float4 p0 = *(const float4*)(kp + 0);
  float4 p1 = *(const float4*)(kp + 4);
  float4 p2 = *(const float4*)(kp + 8);
  float kx[4] = {p0.x, p0.w, p1.z, p2.y};
  float ky[4] = {p0.y, p1.x, p1.w, p2.z};
  float kz[4] = {p0.z, p1.y, p2.x, p2.w};
  uchar4 out;
  unsigned char* o = (unsigned char*)&out;
#pragma unroll
  for (int j = 0; j < 4; j++) {
    float dx = qx - kx[j], dy = qy - ky[j], dz = qz - kz[j];
    float dist = sqrtf(dx * dx + dy * dy + dz * dz);
    float t = (dist / 5.0f) * 32.0f;  // match reference op order
    int bin = (int)t;
    bin = bin > 32 ? 32 : bin;
    o[j] = (unsigned char)bin;
  }
  *(uchar4*)(bins + ((size_t)b * NL + q) * NL + k0) = out;
}

// ---------------- merged QKV projection GEMM, 128x128 tile ----------------
__global__ __launch_bounds__(256) void gemm_qkv(
    const __bf16* __restrict__ Aq, const __bf16* __restrict__ Ak,
    const __bf16* __restrict__ Av, const __bf16* __restrict__ Wqt,
    const __bf16* __restrict__ Wkt, const __bf16* __restrict__ Wvt,
    const float* __restrict__ bq, const float* __restrict__ bk,
    const float* __restrict__ bv, __bf16* __restrict__ Qp,
    __bf16* __restrict__ Kp, __bf16* __restrict__ Vtp) {
  __shared__ __bf16 As[128 * 64];
  __shared__ __bf16 Bs[128 * 64];
  const int tid = threadIdx.x;
  const int lane = tid & 63;
  const int wave = tid >> 6;
  const int z = blockIdx.x >> 8;
  const int r = blockIdx.x & 255;
  const int bm = r & 31;
  const int bn = r >> 5;
  const __bf16* A = (z == 0) ? Aq : (z == 1) ? Ak : Av;
  const __bf16* Bt = (z == 0) ? Wqt : (z == 1) ? Wkt : Wvt;
  const float* bias = (z == 0) ? bq : (z == 1) ? bk : bv;
  __bf16* C = (z == 0) ? Qp : (z == 1) ? Kp : Vtp;

  const int wm = (wave >> 1) * 64;
  const int wn = (wave & 1) * 64;
  f32x4 acc[4][4] = {};
  const __bf16* Abase = A + (size_t)(bm * 128) * ND;
  const __bf16* Bbase = Bt + (size_t)(bn * 128) * ND;

  for (int kt = 0; kt < ND; kt += 64) {
#pragma unroll
    for (int i = 0; i < 4; i++) {
      int lin = i * 256 + tid;
      int row = lin >> 3;
      int c = (lin & 7) ^ (row & 7);
      gload16(Abase + (size_t)row * ND + kt + c * 8, (char*)As + lin * 16);
    }
#pragma unroll
    for (int i = 0; i < 4; i++) {
      int lin = i * 256 + tid;
      int row = lin >> 3;
      int c = (lin & 7) ^ (row & 7);
      gload16(Bbase + (size_t)row * ND + kt + c * 8, (char*)Bs + lin * 16);
    }
    __syncthreads();
#pragma unroll
    for (int kk = 0; kk < 2; kk++) {
      const int cb = kk * 4 + (lane >> 4);
      bf16x8 af[4], bfr[4];
#pragma unroll
      for (int mf = 0; mf < 4; mf++) {
        int rr = wm + mf * 16 + (lane & 15);
        af[mf] = *(const bf16x8*)((const char*)As + rr * 128 + ((cb ^ (rr & 7)) << 4));
      }
#pragma unroll
      for (int nf = 0; nf < 4; nf++) {
        int rr = wn + nf * 16 + (lane & 15);
        bfr[nf] = *(const bf16x8*)((const char*)Bs + rr * 128 + ((cb ^ (rr & 7)) << 4));
      }
      __builtin_amdgcn_s_setprio(1);
#pragma unroll
      for (int mf = 0; mf < 4; mf++)
#pragma unroll
        for (int nf = 0; nf < 4; nf++)
          acc[mf][nf] = __builtin_amdgcn_mfma_f32_16x16x32_bf16(af[mf], bfr[nf],
                                                                acc[mf][nf], 0, 0, 0);
      __builtin_amdgcn_s_setprio(0);
    }
    __syncthreads();
  }

  const int rbase = (lane >> 4) << 2;
  const int cbase = lane & 15;
  if (z < 2) {
#pragma unroll
    for (int mf = 0; mf < 4; mf++)
#pragma unroll
      for (int nf = 0; nf < 4; nf++) {
        int m0 = bm * 128 + wm + mf * 16 + rbase;
        int n = bn * 128 + wn + nf * 16 + cbase;
        float bvv = bias[n];
        int b = m0 >> 11, ls = m0 & (NL - 1);
        int h = n >> 6, d = n & 63;
        __bf16* base = C + ((size_t)((b * NH + h) * NL + ls)) * NHD + d;
#pragma unroll
        for (int j = 0; j < 4; j++)
          base[(size_t)j * NHD] = (__bf16)(acc[mf][nf][j] + bvv);
      }
  } else {
#pragma unroll
    for (int mf = 0; mf < 4; mf++)
#pragma unroll
      for (int nf = 0; nf < 4; nf++) {
        int m0 = bm * 128 + wm + mf * 16 + rbase;
        int n = bn * 128 + wn + nf * 16 + cbase;
        float bvv = bias[n];
        int b = m0 >> 11, ls = m0 & (NL - 1);
        int h = n >> 6, d = n & 63;
        ushort4 u;
        u.x = __builtin_bit_cast(unsigned short, (__bf16)(acc[mf][nf][0] + bvv));
        u.y = __builtin_bit_cast(unsigned short, (__bf16)(acc[mf][nf][1] + bvv));
        u.z = __builtin_bit_cast(unsigned short, (__bf16)(acc[mf][nf][2] + bvv));
        u.w = __builtin_bit_cast(unsigned short, (__bf16)(acc[mf][nf][3] + bvv));
        *(ushort4*)(C + ((size_t)((b * NH + h) * NHD + d)) * NL + ls) = u;
      }
  }
}

// ---------------- output projection GEMM (64x128 tile, f32 out) ----------------
__global__ __launch_bounds__(256) void gemm_out(
    const __bf16* __restrict__ A, const __bf16* __restrict__ Bt,
    const float* __restrict__ bias, float* __restrict__ C) {
  __shared__ __bf16 As[64 * 64];
  __shared__ __bf16 Bs[128 * 64];
  const int tid = threadIdx.x;
  const int lane = tid & 63;
  const int wave = tid >> 6;
  const int nbm = (NB * NL) >> 6;
  const int bm = blockIdx.x % nbm;
  const int bn = blockIdx.x / nbm;
  const int wm = (wave >> 1) * 32;
  const int wn = (wave & 1) * 64;
  f32x4 acc[2][4] = {};
  const __bf16* Abase = A + (size_t)(bm * 64) * ND;
  const __bf16* Bbase = Bt + (size_t)(bn * 128) * ND;

  for (int kt = 0; kt < ND; kt += 64) {
#pragma unroll
    for (int i = 0; i < 2; i++) {
      int lin = i * 256 + tid;
      int row = lin >> 3;
      int c = (lin & 7) ^ (row & 7);
      gload16(Abase + (size_t)row * ND + kt + c * 8, (char*)As + lin * 16);
    }
#pragma unroll
    for (int i = 0; i < 4; i++) {
      int lin = i * 256 + tid;
      int row = lin >> 3;
      int c = (lin & 7) ^ (row & 7);
      gload16(Bbase + (size_t)row * ND + kt + c * 8, (char*)Bs + lin * 16);
    }
    __syncthreads();
#pragma unroll
    for (int kk = 0; kk < 2; kk++) {
      const int cb = kk * 4 + (lane >> 4);
      bf16x8 af[2], bfr[4];
#pragma unroll
      for (int mf = 0; mf < 2; mf++) {
        int rr = wm + mf * 16 + (lane & 15);
        af[mf] = *(const bf16x8*)((const char*)As + rr * 128 + ((cb ^ (rr & 7)) << 4));
      }
#pragma unroll
      for (int nf = 0; nf < 4; nf++) {
        int rr = wn + nf * 16 + (lane & 15);
        bfr[nf] = *(const bf16x8*)((const char*)Bs + rr * 128 + ((cb ^ (rr & 7)) << 4));
      }
      __builtin_amdgcn_s_setprio(1);
#pragma unroll
      for (int mf = 0; mf < 2; mf++)
#pragma unroll
        for (int nf = 0; nf < 4; nf++)
          acc[mf][nf] = __builtin_amdgcn_mfma_f32_16x16x32_bf16(af[mf], bfr[nf],
                                                                acc[mf][nf], 0, 0, 0);
      __builtin_amdgcn_s_setprio(0);
    }
    __syncthreads();
  }

  const int rbase = (lane >> 4) << 2;
  const int cbase = lane & 15;
#pragma unroll
  for (int mf = 0; mf < 2; mf++)
#pragma unroll
    for (int nf = 0; nf < 4; nf++) {
      int m0 = bm * 64 + wm + mf * 16 + rbase;
      int n = bn * 128 + wn + nf * 16 + cbase;
      float bvv = bias[n];
#pragma unroll
      for (int j = 0; j < 4; j++)
        C[(size_t)(m0 + j) * ND + n] = acc[mf][nf][j] + bvv;
    }
}

// ---------------- flash attention: swapped QK^T, no-max softmax ----------------
// Per tile, lane l owns q-row = q0 + (l&15); k-values (l>>4)*4+j+16*kf.
__global__ __launch_bounds__(256) void attn_kernel(
    const __bf16* __restrict__ Q, const __bf16* __restrict__ K,
    const __bf16* __restrict__ Vt, const unsigned char* __restrict__ bins,
    const float* __restrict__ emb, __bf16* __restrict__ outb) {
  __shared__ __bf16 Ks[64 * 64];
  __shared__ __bf16 Vs[64 * 64];
  __shared__ __bf16 Ps[4][16 * 64];
  __shared__ float embl2[33];
  const int tid = threadIdx.x;
  const int lane = tid & 63;
  const int wave = tid >> 6;
  const int qt = blockIdx.x & 31;
  const int h = (blockIdx.x >> 5) & 15;
  const int b = blockIdx.x >> 9;
  if (tid < 33) embl2[tid] = emb[tid * NH + h] * 1.44269504f;
  const int lr = lane & 15;   // q-row within wave tile
  const int lg = lane >> 4;   // k/d sub-group
  const int q0 = qt * 64 + wave * 16;
  const int qrow = q0 + lr;

  const __bf16* Qbase = Q + ((size_t)((b * NH + h) * NL + qrow)) * NHD + lg * 8;
  bf16x8 qf0 = *(const bf16x8*)(Qbase);
  bf16x8 qf1 = *(const bf16x8*)(Qbase + 32);

  const unsigned char* binq = bins + ((size_t)b * NL + qrow) * NL + lg * 4;

  float lsum = 0.f;
  f32x4 oacc[4] = {};
  const __bf16* Kbase = K + ((size_t)(b * NH + h) * NL) * NHD;
  const __bf16* Vbase = Vt + ((size_t)(b * NH + h) * NHD) * NL;
  char* psw = (char*)&Ps[wave][0];
  const int prow_off = lr * 128;
  const int pswz = (lr & 7) << 4;

  for (int kt = 0; kt < NL; kt += 64) {
    // stage K and V tiles (64x64 bf16 each) via global_load_lds
#pragma unroll
    for (int i = 0; i < 2; i++) {
      int lin = i * 256 + tid;
      int row = lin >> 3;
      int c = (lin & 7) ^ (row & 7);
      gload16(Kbase + (size_t)(kt + row) * NHD + c * 8, (char*)Ks + lin * 16);
      gload16(Vbase + (size_t)row * NL + kt + c * 8, (char*)Vs + lin * 16);
    }
    __syncthreads();

    // bins for this tile: 4B per kf (k = kt + kf*16 + lg*4 + j)
    uint32_t bv4[4];
#pragma unroll
    for (int kf = 0; kf < 4; kf++)
      bv4[kf] = *(const uint32_t*)(binq + kt + kf * 16);

    // QK^T swapped: sacc[kf][j] = S[kt + kf*16 + lg*4 + j][qrow]
    f32x4 sacc[4] = {};
#pragma unroll
    for (int kk = 0; kk < 2; kk++) {
      const int cb = kk * 4 + lg;
      bf16x8 aq = (kk == 0) ? qf0 : qf1;
      __builtin_amdgcn_s_setprio(1);
#pragma unroll
      for (int kf = 0; kf < 4; kf++) {
        int rr = kf * 16 + lr;
        bf16x8 kb =
            *(const bf16x8*)((const char*)Ks + rr * 128 + ((cb ^ (rr & 7)) << 4));
        sacc[kf] = __builtin_amdgcn_mfma_f32_16x16x32_bf16(kb, aq, sacc[kf], 0, 0, 0);
      }
      __builtin_amdgcn_s_setprio(0);
    }

    // no-max softmax: p = 2^(s*0.125*log2e + emb*log2e); lane-local lsum
#pragma unroll
    for (int kf = 0; kf < 4; kf++) {
      float p[4];
#pragma unroll
      for (int j = 0; j < 4; j++) {
        int bin = (bv4[kf] >> (8 * j)) & 255;
        p[j] = exp2f(sacc[kf][j] * 0.1803368801f + embl2[bin]);
        lsum += p[j];
      }
      ushort4 u;
      u.x = __builtin_bit_cast(unsigned short, (__bf16)p[0]);
      u.y = __builtin_bit_cast(unsigned short, (__bf16)p[1]);
      u.z = __builtin_bit_cast(unsigned short, (__bf16)p[2]);
      u.w = __builtin_bit_cast(unsigned short, (__bf16)p[3]);
      int col = (kf * 32 + lg * 8) ^ pswz;
      *(ushort4*)(psw + prow_off + col) = u;
    }

    // PV swapped: oacc[df][j] = O^T[df*16 + lg*4 + j][qrow]
#pragma unroll
    for (int kk = 0; kk < 2; kk++) {
      const int cb = kk * 4 + lg;
      bf16x8 pa =
          *(const bf16x8*)(psw + prow_off + ((kk * 64 + lg * 16) ^ pswz));
      __builtin_amdgcn_s_setprio(1);
#pragma unroll
      for (int df = 0; df < 4; df++) {
        int rr = df * 16 + lr;
        bf16x8 vb =
            *(const bf16x8*)((const char*)Vs + rr * 128 + ((cb ^ (rr & 7)) << 4));
        oacc[df] = __builtin_amdgcn_mfma_f32_16x16x32_bf16(vb, pa, oacc[df], 0, 0, 0);
      }
      __builtin_amdgcn_s_setprio(0);
    }
    __syncthreads();
  }

  // final: reduce lsum across the 4 lane-groups sharing this q-row
  lsum += __shfl_xor(lsum, 16, 64);
  lsum += __shfl_xor(lsum, 32, 64);
  float inv = 1.0f / lsum;
  __bf16* obase = outb + ((size_t)(b * NL + qrow)) * ND + h * NHD + lg * 4;
#pragma unroll
  for (int df = 0; df < 4; df++) {
    ushort4 u;
    u.x = __builtin_bit_cast(unsigned short, (__bf16)(oacc[df][0] * inv));
    u.y = __builtin_bit_cast(unsigned short, (__bf16)(oacc[df][1] * inv));
    u.z = __builtin_bit_cast(unsigned short, (__bf16)(oacc[df][2] * inv));
    u.w = __builtin_bit_cast(unsigned short, (__bf16)(oacc[df][3] * inv));
    *(ushort4*)(obase + df * 16) = u;
  }
}

extern "C" void kernel_launch(void* const* d_in, const int* in_sizes, int n_in,
                              void* d_out, int out_size, void* d_ws, size_t ws_size,
                              hipStream_t stream) {
  const float* query = (const float*)d_in[0];
  const float* key = (const float*)d_in[1];
  const float* value = (const float*)d_in[2];
  const float* pos = (const float*)d_in[3];
  const float* Wq = (const float*)d_in[4];
  const float* bq = (const float*)d_in[5];
  const float* Wk = (const float*)d_in[6];
  const float* bk = (const float*)d_in[7];
  const float* Wv = (const float*)d_in[8];
  const float* bv = (const float*)d_in[9];
  const float* Wo = (const float*)d_in[10];
  const float* bo = (const float*)d_in[11];
  const float* emb = (const float*)d_in[12];

  if (ws_size < (64ull << 20)) return;  // need 64MB scratch
  char* ws = (char*)d_ws;
  const size_t MB = 1ull << 20;
  __bf16* qb = (__bf16*)(ws + 0 * MB);  // reused as attn output buffer
  __bf16* kb = (__bf16*)(ws + 8 * MB);
  __bf16* vb = (__bf16*)(ws + 16 * MB);
  __bf16* Wq_t = (__bf16*)(ws + 24 * MB);
  __bf16* Wk_t = (__bf16*)(ws + 26 * MB);
  __bf16* Wv_t = (__bf16*)(ws + 28 * MB);
  __bf16* Wo_t = (__bf16*)(ws + 30 * MB);
  __bf16* Qp = (__bf16*)(ws + 32 * MB);
  __bf16* Kp = (__bf16*)(ws + 40 * MB);
  __bf16* Vtp = (__bf16*)(ws + 48 * MB);
  unsigned char* binsb = (unsigned char*)(ws + 56 * MB);
  __bf16* attnb = qb;

  const int n4 = NB * NL * ND / 4;
  cvt3_f32_bf16<<<dim3(n4 / 256, 3), 256, 0, stream>>>(query, key, value, qb, kb, vb,
                                                       n4);
  transpose_cvt4<<<dim3(32, 32, 4), dim3(32, 8), 0, stream>>>(Wq, Wk, Wv, Wo, Wq_t,
                                                              Wk_t, Wv_t, Wo_t);
  bins_kernel<<<dim3(NL / 1024, NL, NB), 256, 0, stream>>>(pos, binsb);

  gemm_qkv<<<3 * 256, 256, 0, stream>>>(qb, kb, vb, Wq_t, Wk_t, Wv_t, bq, bk, bv, Qp,
                                        Kp, Vtp);

  attn_kernel<<<NB * NH * (NL / 64), 256, 0, stream>>>(Qp, Kp, Vtp, binsb, emb, attnb);

  gemm_out<<<((NB * NL) / 64) * (ND / 128), 256, 0, stream>>>(attnb, Wo_t, bo,
                                                              (float*)d_out);
}